// Round 7
// baseline (5627.270 us; speedup 1.0000x reference)
//
#include <hip/hip_runtime.h>

#define T_DIM 512
#define B_DIM 64
#define F_DIM 128
#define H_DIM 512

typedef _Float16 f16x8 __attribute__((ext_vector_type(8)));
typedef _Float16 f16x4 __attribute__((ext_vector_type(4)));
typedef float f32x4 __attribute__((ext_vector_type(4)));

// ---------------------------------------------------------------------------
// prep: whT16[l][j][k] f16  (wh[k][j] transposed, for A-fragment loads)
// ---------------------------------------------------------------------------
__global__ void prep_whT16(_Float16* __restrict__ dst, const float* __restrict__ w0,
                           const float* __restrict__ w1, const float* __restrict__ w2) {
  const long total = 3L * 512 * 512;
  for (long idx = (long)blockIdx.x * blockDim.x + threadIdx.x; idx < total;
       idx += (long)gridDim.x * blockDim.x) {
    int l = (int)(idx >> 18);
    int rem = (int)(idx & 262143);
    int j = rem >> 9, k = rem & 511;
    const float* src = (l == 0) ? w0 : (l == 1) ? w1 : w2;
    dst[idx] = (_Float16)src[k * 512 + j];
  }
}

// ---------------------------------------------------------------------------
// prep: Wcat^T [l][n=512][kc=640] f16
// ---------------------------------------------------------------------------
__global__ void prep_wcat(_Float16* __restrict__ dst,
                          const float* __restrict__ wi0, const float* __restrict__ ws0,
                          const float* __restrict__ wi1, const float* __restrict__ ws1,
                          const float* __restrict__ wi2, const float* __restrict__ ws2) {
  const long total = 3L * 512 * 640;
  for (long idx = (long)blockIdx.x * blockDim.x + threadIdx.x; idx < total;
       idx += (long)gridDim.x * blockDim.x) {
    int l = (int)(idx / 327680);
    int rem = (int)(idx % 327680);
    int n = rem / 640, kc = rem % 640;
    int inK = (l == 0) ? 128 : 512;
    const float* wi = (l == 0) ? wi0 : (l == 1) ? wi1 : wi2;
    const float* ws = (l == 0) ? ws0 : (l == 1) ? ws1 : ws2;
    float v = 0.f;
    if (kc < inK) v = wi[kc * 512 + n];
    else if (kc < inK + 128) v = ws[(kc - inK) * 512 + n];
    dst[idx] = (_Float16)v;
  }
}

// ---------------------------------------------------------------------------
// build A' panel f16 (unchanged, verified)
// ---------------------------------------------------------------------------
__global__ void build_A(_Float16* __restrict__ Abuf, const float* __restrict__ xin,
                        const float* __restrict__ prev, int n, int inK, int scale,
                        int layer) {
  const int Kcat = inK + 128;
  const long total = (long)n * 64 * Kcat;
  for (long idx = (long)blockIdx.x * blockDim.x + threadIdx.x; idx < total;
       idx += (long)gridDim.x * blockDim.x) {
    int k = (int)(idx % Kcat);
    long r = idx / Kcat;
    int b = (int)(r & 63);
    int t = (int)(r >> 6);
    float v;
    if (k < inK) {
      if (layer == 0) v = xin[((long)b * T_DIM + t) * F_DIM + k];
      else v = prev[((long)(t + scale - 1) * B_DIM + b) * H_DIM + k];
    } else {
      int kk = k - inK;
      int t0 = t + scale - 1;
      float s = 0.f;
      for (int w = 0; w < scale; ++w) s += xin[((long)b * T_DIM + t0 + w) * F_DIM + kk];
      v = s * (1.f / scale);
    }
    Abuf[idx] = (_Float16)v;
  }
}

// ---------------------------------------------------------------------------
// f16 MFMA GEMM (unchanged, verified)
// ---------------------------------------------------------------------------
__global__ __launch_bounds__(256) void gemm_f16(const _Float16* __restrict__ A,
                                                const _Float16* __restrict__ Bt,
                                                float* __restrict__ C, int Mrows,
                                                int Kcat) {
  __shared__ _Float16 As[128][72];
  __shared__ _Float16 Bs[128][72];
  const int tid = threadIdx.x;
  const int tn = blockIdx.x, tm = blockIdx.y;
  const int lane = tid & 63, wid = tid >> 6;
  const int wm = wid >> 1, wn = wid & 1;
  f32x4 acc[4][4] = {};
  const int nK = Kcat >> 6;
  const int lrow = tid >> 3, lkc = (tid & 7) * 8;

  for (int kt = 0; kt < nK; ++kt) {
    for (int r = 0; r < 4; ++r) {
      int row = r * 32 + lrow;
      int grow = tm * 128 + row;
      uint4 va = make_uint4(0u, 0u, 0u, 0u);
      if (grow < Mrows) va = *(const uint4*)&A[(size_t)grow * Kcat + kt * 64 + lkc];
      *(uint4*)&As[row][lkc] = va;
      uint4 vb = *(const uint4*)&Bt[(size_t)(tn * 128 + row) * 640 + kt * 64 + lkc];
      *(uint4*)&Bs[row][lkc] = vb;
    }
    __syncthreads();
#pragma unroll
    for (int kk = 0; kk < 64; kk += 32) {
      f16x8 af[4], bf[4];
#pragma unroll
      for (int mt = 0; mt < 4; ++mt)
        af[mt] = *(const f16x8*)&As[wm * 64 + mt * 16 + (lane & 15)][kk + (lane >> 4) * 8];
#pragma unroll
      for (int nt = 0; nt < 4; ++nt)
        bf[nt] = *(const f16x8*)&Bs[wn * 64 + nt * 16 + (lane & 15)][kk + (lane >> 4) * 8];
#pragma unroll
      for (int mt = 0; mt < 4; ++mt)
#pragma unroll
        for (int nt = 0; nt < 4; ++nt)
          acc[mt][nt] = __builtin_amdgcn_mfma_f32_16x16x32_f16(af[mt], bf[nt], acc[mt][nt], 0, 0, 0);
    }
    __syncthreads();
  }

  const int crow0 = tm * 128 + wm * 64 + (lane >> 4) * 4;
  const int ccol0 = tn * 128 + wn * 64 + (lane & 15);
#pragma unroll
  for (int mt = 0; mt < 4; ++mt)
#pragma unroll
    for (int q = 0; q < 4; ++q) {
      int grow = crow0 + mt * 16 + q;
      if (grow < Mrows) {
#pragma unroll
        for (int nt = 0; nt < 4; ++nt)
          C[(size_t)grow * 512 + ccol0 + nt * 16] = acc[mt][nt][q];
      }
    }
}

// ---------------------------------------------------------------------------
// rec_fused v5: 512 thr (8 waves, 2/SIMD). Honest 256-reg fit:
//   kb 0..9  -> registers  (bfr[4][10] = 160 regs)
//   kb 10..13-> LDS Blds   (128 KB)
//   kb 14,15 -> streamed from whT (L2) through one 16-reg buffer per step
// Wave-parity staggered kb sequence (seqO = seqE rot 2) so the 2 waves/SIMD
// use different pipes at the same time. setprio(1) around the MFMA block.
// Same verified hstage slot map, single lgkmcnt-only barrier per step.
// ---------------------------------------------------------------------------
#define AFRD(kb) (*(const f16x8*)&hs[((kb)*64 + u * 16 + (bq ^ (u & 1))) * 8])
#define BLRD(kb, nt) \
  (*(const f16x8*)&Blds[((((kb)-10) * 32 + gnb + (nt)) * 64 + lane) * 8])
#define GLOAD(kb, nt) \
  (*(const f16x8*)&whT[(size_t)(colbase + (nt)*16 + bq) * 512 + (kb)*32 + u * 8])

template <int P>
__device__ __forceinline__ void mfma_block(f32x4 (&acc)[4], const _Float16* hs,
                                           const _Float16* Blds,
                                           const _Float16* whT,
                                           const f16x8 (&bfr)[4][10], int u, int bq,
                                           int lane, int gnb, int colbase) {
  constexpr int seqE[16] = {10, 0, 1, 2, 11, 3, 4, 14, 12, 5, 6, 7, 13, 8, 9, 15};
  constexpr int seqO[16] = {1, 2, 11, 3, 4, 14, 12, 5, 6, 7, 13, 8, 9, 15, 10, 0};
  constexpr int lnxE[16] = {11, -1, -1, -1, 12, -1, -1, -1, 13, -1, -1, -1, -1, -1, -1, -1};
  constexpr int lnxO[16] = {-1, -1, 12, -1, -1, -1, 13, -1, -1, -1, 10, -1, -1, -1, -1, -1};
  const int(&seq)[16] = P ? seqO : seqE;
  const int(&lnx)[16] = P ? lnxO : lnxE;

  f16x8 afr[4];
#pragma unroll
  for (int i = 0; i < 4; ++i) afr[i] = AFRD(seq[i]);
  f16x8 blr[4];
#pragma unroll
  for (int nt = 0; nt < 4; ++nt) blr[nt] = BLRD(P ? 11 : 10, nt);
  f16x8 gfr[4];
#pragma unroll
  for (int nt = 0; nt < 4; ++nt) gfr[nt] = GLOAD(14, nt);

  __builtin_amdgcn_s_setprio(1);
#pragma unroll
  for (int i = 0; i < 16; ++i) {
    const int kb = seq[i];
    f16x8 a = afr[i & 3];
    if (i + 4 < 16) afr[i & 3] = AFRD(seq[i + 4]);
    if (kb < 10) {
#pragma unroll
      for (int nt = 0; nt < 4; ++nt)
        acc[nt] = __builtin_amdgcn_mfma_f32_16x16x32_f16(bfr[nt][kb], a, acc[nt], 0, 0, 0);
    } else if (kb < 14) {
      f16x8 w[4];
#pragma unroll
      for (int nt = 0; nt < 4; ++nt) w[nt] = blr[nt];
      if (lnx[i] >= 0) {
#pragma unroll
        for (int nt = 0; nt < 4; ++nt) blr[nt] = BLRD(lnx[i], nt);
      }
#pragma unroll
      for (int nt = 0; nt < 4; ++nt)
        acc[nt] = __builtin_amdgcn_mfma_f32_16x16x32_f16(w[nt], a, acc[nt], 0, 0, 0);
    } else if (kb == 14) {
      f16x8 w[4];
#pragma unroll
      for (int nt = 0; nt < 4; ++nt) w[nt] = gfr[nt];
#pragma unroll
      for (int nt = 0; nt < 4; ++nt) gfr[nt] = GLOAD(15, nt);
#pragma unroll
      for (int nt = 0; nt < 4; ++nt)
        acc[nt] = __builtin_amdgcn_mfma_f32_16x16x32_f16(w[nt], a, acc[nt], 0, 0, 0);
    } else {
#pragma unroll
      for (int nt = 0; nt < 4; ++nt)
        acc[nt] = __builtin_amdgcn_mfma_f32_16x16x32_f16(gfr[nt], a, acc[nt], 0, 0, 0);
    }
  }
  __builtin_amdgcn_s_setprio(0);
}

__global__ __launch_bounds__(512, 2) void rec_fused(float* __restrict__ po,
                                                    const _Float16* __restrict__ whT,
                                                    int n) {
  const int tid = threadIdx.x;
  const int b0g = blockIdx.x * 16;
  const int lane = tid & 63, wid = tid >> 6;  // wid 0..7
  const int colbase = wid * 64;               // wave owns cols [64w, 64w+64)
  const int bq = lane & 15;                   // batch (C column)
  const int u = lane >> 4;                    // k-chunk / j-subrow selector

  __shared__ _Float16 hstage[2][16 * 512];    // 32 KB
  __shared__ _Float16 Blds[4 * 32 * 64 * 8];  // 128 KB, A-frag order kb 10..13

  // one-time: fill Blds (frag-order gather from whT); 8192 uint4, 512 thr
  {
    uint4* B4 = (uint4*)Blds;
    for (int p = 0; p < 16; ++p) {
      int flat = p * 512 + tid;  // 0..8191
      int l = flat & 63;
      int gn = (flat >> 6) & 31;
      int kbl = flat >> 11;  // 0..3 -> kb 10..13
      B4[flat] = *(const uint4*)&whT[(size_t)(gn * 16 + (l & 15)) * 512 +
                                     (kbl + 10) * 32 + (l >> 4) * 8];
    }
  }
  // one-time: weight A-frags kb 0..9 (4 n-tiles x 10 kb = 160 regs)
  f16x8 bfr[4][10];
  {
#pragma unroll
    for (int nt = 0; nt < 4; ++nt) {
      const int j = colbase + nt * 16 + bq;
#pragma unroll
      for (int kb = 0; kb < 10; ++kb)
        bfr[nt][kb] = *(const f16x8*)&whT[(size_t)j * 512 + kb * 32 + u * 8];
    }
  }
  __syncthreads();  // Blds ready

  const int gnb = wid * 4;  // global n-tile base for this wave
  // lane's global base: batch row (b0g+bq), col block colbase + u*4
  const size_t base = (size_t)(b0g + bq) * 512 + colbase + u * 4;

  for (int t = 0; t < n; ++t) {
    const float* pc = po + (size_t)t * (B_DIM * H_DIM) + base;
    f32x4 acc[4];
#pragma unroll
    for (int nt = 0; nt < 4; ++nt) acc[nt] = *(const f32x4*)&pc[nt * 16];

    if (t > 0) {
      const _Float16* hs = hstage[(t - 1) & 1];
      if (wid & 1)
        mfma_block<1>(acc, hs, Blds, whT, bfr, u, bq, lane, gnb, colbase);
      else
        mfma_block<0>(acc, hs, Blds, whT, bfr, u, bq, lane, gnb, colbase);
    }

    // tanh; vectorized h16 write (ds_write_b64) + f32 out write (dwordx4)
    _Float16* hw = hstage[t & 1];
    float* pw = po + (size_t)t * (B_DIM * H_DIM) + base;
#pragma unroll
    for (int nt = 0; nt < 4; ++nt) {
      const int J = colbase + nt * 16 + u * 4;
      const int slot = (J >> 5) * 64 + ((J >> 3) & 3) * 16 + (bq ^ ((J >> 3) & 1));
      f16x4 h4;
#pragma unroll
      for (int q = 0; q < 4; ++q) {
        float a = acc[nt][q];
        float e = __builtin_amdgcn_exp2f(a * 2.8853900817779268f);
        float h = 1.f - 2.f * __builtin_amdgcn_rcpf(e + 1.f);
        acc[nt][q] = h;
        h4[q] = (_Float16)h;
      }
      *(f16x4*)&hw[slot * 8 + (J & 7)] = h4;
      *(f32x4*)&pw[nt * 16] = acc[nt];
    }
    // single barrier: drain LDS writes only (no vmcnt drain)
    asm volatile("s_waitcnt lgkmcnt(0)\n\ts_barrier" ::: "memory");
  }
}

// ---------------------------------------------------------------------------
extern "C" void kernel_launch(void* const* d_in, const int* in_sizes, int n_in,
                              void* d_out, int out_size, void* d_ws, size_t ws_size,
                              hipStream_t stream) {
  const float* inputs = (const float*)d_in[0];
  const float* wi[3] = {(const float*)d_in[1], (const float*)d_in[4], (const float*)d_in[7]};
  const float* wsm[3] = {(const float*)d_in[2], (const float*)d_in[5], (const float*)d_in[8]};
  const float* wh[3] = {(const float*)d_in[3], (const float*)d_in[6], (const float*)d_in[9]};
  float* out = (float*)d_out;

  char* wsp = (char*)d_ws;
  _Float16* whT16 = (_Float16*)wsp;                 // 3*512*512*2 = 1,572,864
  _Float16* wcat = (_Float16*)(wsp + 1572864);      // 3*512*640*2 = 1,966,080
  _Float16* Abuf = (_Float16*)(wsp + 3538944);      // 32704*640*2 = 41,861,120

  prep_whT16<<<1024, 256, 0, stream>>>(whT16, wh[0], wh[1], wh[2]);
  prep_wcat<<<1024, 256, 0, stream>>>(wcat, wi[0], wsm[0], wi[1], wsm[1], wi[2], wsm[2]);

  const int nL[3] = {511, 509, 505};
  const long offL[3] = {0L, 511L * 64 * 512, (511L + 509L) * 64 * 512};
  const int inKL[3] = {128, 512, 512};
  const int scaleL[3] = {1, 2, 4};

  for (int l = 0; l < 3; ++l) {
    const int n = nL[l], inK = inKL[l], Kcat = inK + 128;
    const float* prev = (l == 0) ? nullptr : out + offL[l - 1];
    build_A<<<4096, 256, 0, stream>>>(Abuf, inputs, prev, n, inK, scaleL[l], l);
    const int Mrows = n * 64;
    const int Mt = (Mrows + 127) / 128;
    gemm_f16<<<dim3(4, Mt), 256, 0, stream>>>(Abuf, wcat + (size_t)l * 512 * 640,
                                              out + offL[l], Mrows, Kcat);
    rec_fused<<<4, 512, 0, stream>>>(out + offL[l], whT16 + (size_t)l * 262144, n);
  }
}

// Round 8
// 3538.264 us; speedup vs baseline: 1.5904x; 1.5904x over previous
//
#include <hip/hip_runtime.h>

#define T_DIM 512
#define B_DIM 64
#define F_DIM 128
#define H_DIM 512

typedef _Float16 f16x8 __attribute__((ext_vector_type(8)));
typedef _Float16 f16x4 __attribute__((ext_vector_type(4)));
typedef float f32x4 __attribute__((ext_vector_type(4)));

// ---------------------------------------------------------------------------
// prep: whT16[l][j][k] f16  (wh[k][j] transposed, for A-fragment loads)
// ---------------------------------------------------------------------------
__global__ void prep_whT16(_Float16* __restrict__ dst, const float* __restrict__ w0,
                           const float* __restrict__ w1, const float* __restrict__ w2) {
  const long total = 3L * 512 * 512;
  for (long idx = (long)blockIdx.x * blockDim.x + threadIdx.x; idx < total;
       idx += (long)gridDim.x * blockDim.x) {
    int l = (int)(idx >> 18);
    int rem = (int)(idx & 262143);
    int j = rem >> 9, k = rem & 511;
    const float* src = (l == 0) ? w0 : (l == 1) ? w1 : w2;
    dst[idx] = (_Float16)src[k * 512 + j];
  }
}

// ---------------------------------------------------------------------------
// prep: Wcat^T [l][n=512][kc=640] f16
// ---------------------------------------------------------------------------
__global__ void prep_wcat(_Float16* __restrict__ dst,
                          const float* __restrict__ wi0, const float* __restrict__ ws0,
                          const float* __restrict__ wi1, const float* __restrict__ ws1,
                          const float* __restrict__ wi2, const float* __restrict__ ws2) {
  const long total = 3L * 512 * 640;
  for (long idx = (long)blockIdx.x * blockDim.x + threadIdx.x; idx < total;
       idx += (long)gridDim.x * blockDim.x) {
    int l = (int)(idx / 327680);
    int rem = (int)(idx % 327680);
    int n = rem / 640, kc = rem % 640;
    int inK = (l == 0) ? 128 : 512;
    const float* wi = (l == 0) ? wi0 : (l == 1) ? wi1 : wi2;
    const float* ws = (l == 0) ? ws0 : (l == 1) ? ws1 : ws2;
    float v = 0.f;
    if (kc < inK) v = wi[kc * 512 + n];
    else if (kc < inK + 128) v = ws[(kc - inK) * 512 + n];
    dst[idx] = (_Float16)v;
  }
}

// ---------------------------------------------------------------------------
// build A' panel f16 (unchanged, verified)
// ---------------------------------------------------------------------------
__global__ void build_A(_Float16* __restrict__ Abuf, const float* __restrict__ xin,
                        const float* __restrict__ prev, int n, int inK, int scale,
                        int layer) {
  const int Kcat = inK + 128;
  const long total = (long)n * 64 * Kcat;
  for (long idx = (long)blockIdx.x * blockDim.x + threadIdx.x; idx < total;
       idx += (long)gridDim.x * blockDim.x) {
    int k = (int)(idx % Kcat);
    long r = idx / Kcat;
    int b = (int)(r & 63);
    int t = (int)(r >> 6);
    float v;
    if (k < inK) {
      if (layer == 0) v = xin[((long)b * T_DIM + t) * F_DIM + k];
      else v = prev[((long)(t + scale - 1) * B_DIM + b) * H_DIM + k];
    } else {
      int kk = k - inK;
      int t0 = t + scale - 1;
      float s = 0.f;
      for (int w = 0; w < scale; ++w) s += xin[((long)b * T_DIM + t0 + w) * F_DIM + kk];
      v = s * (1.f / scale);
    }
    Abuf[idx] = (_Float16)v;
  }
}

// ---------------------------------------------------------------------------
// f16 MFMA GEMM (unchanged, verified)
// ---------------------------------------------------------------------------
__global__ __launch_bounds__(256) void gemm_f16(const _Float16* __restrict__ A,
                                                const _Float16* __restrict__ Bt,
                                                float* __restrict__ C, int Mrows,
                                                int Kcat) {
  __shared__ _Float16 As[128][72];
  __shared__ _Float16 Bs[128][72];
  const int tid = threadIdx.x;
  const int tn = blockIdx.x, tm = blockIdx.y;
  const int lane = tid & 63, wid = tid >> 6;
  const int wm = wid >> 1, wn = wid & 1;
  f32x4 acc[4][4] = {};
  const int nK = Kcat >> 6;
  const int lrow = tid >> 3, lkc = (tid & 7) * 8;

  for (int kt = 0; kt < nK; ++kt) {
    for (int r = 0; r < 4; ++r) {
      int row = r * 32 + lrow;
      int grow = tm * 128 + row;
      uint4 va = make_uint4(0u, 0u, 0u, 0u);
      if (grow < Mrows) va = *(const uint4*)&A[(size_t)grow * Kcat + kt * 64 + lkc];
      *(uint4*)&As[row][lkc] = va;
      uint4 vb = *(const uint4*)&Bt[(size_t)(tn * 128 + row) * 640 + kt * 64 + lkc];
      *(uint4*)&Bs[row][lkc] = vb;
    }
    __syncthreads();
#pragma unroll
    for (int kk = 0; kk < 64; kk += 32) {
      f16x8 af[4], bf[4];
#pragma unroll
      for (int mt = 0; mt < 4; ++mt)
        af[mt] = *(const f16x8*)&As[wm * 64 + mt * 16 + (lane & 15)][kk + (lane >> 4) * 8];
#pragma unroll
      for (int nt = 0; nt < 4; ++nt)
        bf[nt] = *(const f16x8*)&Bs[wn * 64 + nt * 16 + (lane & 15)][kk + (lane >> 4) * 8];
#pragma unroll
      for (int mt = 0; mt < 4; ++mt)
#pragma unroll
        for (int nt = 0; nt < 4; ++nt)
          acc[mt][nt] = __builtin_amdgcn_mfma_f32_16x16x32_f16(af[mt], bf[nt], acc[mt][nt], 0, 0, 0);
    }
    __syncthreads();
  }

  const int crow0 = tm * 128 + wm * 64 + (lane >> 4) * 4;
  const int ccol0 = tn * 128 + wn * 64 + (lane & 15);
#pragma unroll
  for (int mt = 0; mt < 4; ++mt)
#pragma unroll
    for (int q = 0; q < 4; ++q) {
      int grow = crow0 + mt * 16 + q;
      if (grow < Mrows) {
#pragma unroll
        for (int nt = 0; nt < 4; ++nt)
          C[(size_t)grow * 512 + ccol0 + nt * 16] = acc[mt][nt][q];
      }
    }
}

// ---------------------------------------------------------------------------
// rec_fused v6: 512 thr (8 waves, 2/SIMD). Partition of the 16 k-blocks:
//   kb 0..9   -> VGPRs (bfr[4][10] = 160 regs), residency FORCED via
//                opaque-def asm ("+v") so the allocator cannot rematerialize
//                the loads inside the loop (the R6/R7 failure: VGPR=128).
//   kb 10..13 -> LDS Blds (128 KB, frag-order)
//   kb 14,15  -> streamed from whT (L2) through gfr with >=8-position cover
// acc starts at 0; pre folded in at tanh time so pre-loads get the whole
// MFMA phase as latency cover. Single lgkmcnt-only barrier per step.
// ---------------------------------------------------------------------------
__global__ __launch_bounds__(512, 2) void rec_fused(float* __restrict__ po,
                                                    const _Float16* __restrict__ whT,
                                                    int n) {
  const int tid = threadIdx.x;
  const int b0g = blockIdx.x * 16;
  const int lane = tid & 63, wid = tid >> 6;  // wid 0..7
  const int colbase = wid * 64;               // wave owns cols [64w, 64w+64)
  const int bq = lane & 15;                   // batch (C column)
  const int u = lane >> 4;                    // k-chunk / j-subrow selector

  __shared__ _Float16 hstage[2][16 * 512];    // 32 KB
  __shared__ _Float16 Blds[4 * 32 * 64 * 8];  // 128 KB, A-frag order kb 10..13

  // one-time: fill Blds (frag-order gather from whT); 8192 uint4, 512 thr
  {
    uint4* B4 = (uint4*)Blds;
    for (int p = 0; p < 16; ++p) {
      int flat = p * 512 + tid;  // 0..8191
      int l = flat & 63;
      int gn = (flat >> 6) & 31;
      int kbl = flat >> 11;  // 0..3 -> kb 10..13
      B4[flat] = *(const uint4*)&whT[(size_t)(gn * 16 + (l & 15)) * 512 +
                                     (kbl + 10) * 32 + (l >> 4) * 8];
    }
  }
  // one-time: weight A-frags kb 0..9 -> registers, residency forced
  f16x8 bfr[4][10];
  {
#pragma unroll
    for (int nt = 0; nt < 4; ++nt) {
      const int j = colbase + nt * 16 + bq;
#pragma unroll
      for (int kb = 0; kb < 10; ++kb)
        bfr[nt][kb] = *(const f16x8*)&whT[(size_t)j * 512 + kb * 32 + u * 8];
    }
#pragma unroll
    for (int nt = 0; nt < 4; ++nt)
#pragma unroll
      for (int kb = 0; kb < 10; ++kb)
        asm volatile("" : "+v"(bfr[nt][kb]));  // opaque def: no remat, no reload
  }
  __syncthreads();  // Blds ready

  const int gnb = wid * 4;  // global n-tile base for this wave
  const size_t base = (size_t)(b0g + bq) * 512 + colbase + u * 4;

#define AFRD(kb) (*(const f16x8*)&hs[((kb)*64 + u * 16 + (bq ^ (u & 1))) * 8])
#define BLRD(kb, nt) \
  (*(const f16x8*)&Blds[((((kb)-10) * 32 + gnb + (nt)) * 64 + lane) * 8])
#define GLOAD(kb, nt) \
  (*(const f16x8*)&whT[(size_t)(colbase + (nt)*16 + bq) * 512 + (kb)*32 + u * 8])

  for (int t = 0; t < n; ++t) {
    // pre-loads issued at loop top; consumed only at tanh (full MFMA cover)
    const float* pc = po + (size_t)t * (B_DIM * H_DIM) + base;
    f32x4 pre[4];
#pragma unroll
    for (int nt = 0; nt < 4; ++nt) pre[nt] = *(const f32x4*)&pc[nt * 16];

    f32x4 acc[4] = {};

    if (t > 0) {
      const _Float16* hs = hstage[(t - 1) & 1];
      // kb order: LDS kbs every ~4, streamed kbs late with cover
      constexpr int seq[16] = {10, 0, 1, 2, 3, 11, 4, 5, 14, 12, 6, 7, 13, 8, 9, 15};
      constexpr int lnx[16] = {11, -1, -1, -1, -1, 12, -1, -1, -1, 13, -1, -1, -1, -1, -1, -1};
      f16x8 afr[4];
#pragma unroll
      for (int i = 0; i < 4; ++i) afr[i] = AFRD(seq[i]);
      f16x8 blr[4];
#pragma unroll
      for (int nt = 0; nt < 4; ++nt) blr[nt] = BLRD(10, nt);
      f16x8 gfr[4];
#pragma unroll
      for (int nt = 0; nt < 4; ++nt) gfr[nt] = GLOAD(14, nt);

#pragma unroll
      for (int i = 0; i < 16; ++i) {
        const int kb = seq[i];
        f16x8 a = afr[i & 3];
        if (i + 4 < 16) afr[i & 3] = AFRD(seq[i + 4]);
        if (kb < 10) {
#pragma unroll
          for (int nt = 0; nt < 4; ++nt)
            acc[nt] = __builtin_amdgcn_mfma_f32_16x16x32_f16(bfr[nt][kb], a, acc[nt], 0, 0, 0);
        } else if (kb < 14) {
          f16x8 w[4];
#pragma unroll
          for (int nt = 0; nt < 4; ++nt) w[nt] = blr[nt];
          if (lnx[i] >= 0) {
#pragma unroll
            for (int nt = 0; nt < 4; ++nt) blr[nt] = BLRD(lnx[i], nt);
          }
#pragma unroll
          for (int nt = 0; nt < 4; ++nt)
            acc[nt] = __builtin_amdgcn_mfma_f32_16x16x32_f16(w[nt], a, acc[nt], 0, 0, 0);
        } else if (kb == 14) {
          f16x8 w[4];
#pragma unroll
          for (int nt = 0; nt < 4; ++nt) w[nt] = gfr[nt];
#pragma unroll
          for (int nt = 0; nt < 4; ++nt) gfr[nt] = GLOAD(15, nt);
#pragma unroll
          for (int nt = 0; nt < 4; ++nt)
            acc[nt] = __builtin_amdgcn_mfma_f32_16x16x32_f16(w[nt], a, acc[nt], 0, 0, 0);
        } else {
#pragma unroll
          for (int nt = 0; nt < 4; ++nt)
            acc[nt] = __builtin_amdgcn_mfma_f32_16x16x32_f16(gfr[nt], a, acc[nt], 0, 0, 0);
        }
      }
    }

    // tanh(acc + pre); vectorized h16 write (ds_write_b64) + f32 out (dwordx4)
    _Float16* hw = hstage[t & 1];
    float* pw = po + (size_t)t * (B_DIM * H_DIM) + base;
#pragma unroll
    for (int nt = 0; nt < 4; ++nt) {
      const int J = colbase + nt * 16 + u * 4;
      const int slot = (J >> 5) * 64 + ((J >> 3) & 3) * 16 + (bq ^ ((J >> 3) & 1));
      f16x4 h4;
#pragma unroll
      for (int q = 0; q < 4; ++q) {
        float a = acc[nt][q] + pre[nt][q];
        float e = __builtin_amdgcn_exp2f(a * 2.8853900817779268f);
        float h = 1.f - 2.f * __builtin_amdgcn_rcpf(e + 1.f);
        acc[nt][q] = h;
        h4[q] = (_Float16)h;
      }
      *(f16x4*)&hw[slot * 8 + (J & 7)] = h4;
      *(f32x4*)&pw[nt * 16] = acc[nt];
    }
    // single barrier: drain LDS writes only (no vmcnt drain)
    asm volatile("s_waitcnt lgkmcnt(0)\n\ts_barrier" ::: "memory");
  }
#undef AFRD
#undef BLRD
#undef GLOAD
}

// ---------------------------------------------------------------------------
extern "C" void kernel_launch(void* const* d_in, const int* in_sizes, int n_in,
                              void* d_out, int out_size, void* d_ws, size_t ws_size,
                              hipStream_t stream) {
  const float* inputs = (const float*)d_in[0];
  const float* wi[3] = {(const float*)d_in[1], (const float*)d_in[4], (const float*)d_in[7]};
  const float* wsm[3] = {(const float*)d_in[2], (const float*)d_in[5], (const float*)d_in[8]};
  const float* wh[3] = {(const float*)d_in[3], (const float*)d_in[6], (const float*)d_in[9]};
  float* out = (float*)d_out;

  char* wsp = (char*)d_ws;
  _Float16* whT16 = (_Float16*)wsp;                 // 3*512*512*2 = 1,572,864
  _Float16* wcat = (_Float16*)(wsp + 1572864);      // 3*512*640*2 = 1,966,080
  _Float16* Abuf = (_Float16*)(wsp + 3538944);      // 32704*640*2 = 41,861,120

  prep_whT16<<<1024, 256, 0, stream>>>(whT16, wh[0], wh[1], wh[2]);
  prep_wcat<<<1024, 256, 0, stream>>>(wcat, wi[0], wsm[0], wi[1], wsm[1], wi[2], wsm[2]);

  const int nL[3] = {511, 509, 505};
  const long offL[3] = {0L, 511L * 64 * 512, (511L + 509L) * 64 * 512};
  const int inKL[3] = {128, 512, 512};
  const int scaleL[3] = {1, 2, 4};

  for (int l = 0; l < 3; ++l) {
    const int n = nL[l], inK = inKL[l], Kcat = inK + 128;
    const float* prev = (l == 0) ? nullptr : out + offL[l - 1];
    build_A<<<4096, 256, 0, stream>>>(Abuf, inputs, prev, n, inK, scaleL[l], l);
    const int Mrows = n * 64;
    const int Mt = (Mrows + 127) / 128;
    gemm_f16<<<dim3(4, Mt), 256, 0, stream>>>(Abuf, wcat + (size_t)l * 512 * 640,
                                              out + offL[l], Mrows, Kcat);
    rec_fused<<<4, 512, 0, stream>>>(out + offL[l], whT16 + (size_t)l * 262144, n);
  }
}

// Round 9
// 2963.636 us; speedup vs baseline: 1.8988x; 1.1939x over previous
//
#include <hip/hip_runtime.h>

#define T_DIM 512
#define B_DIM 64
#define F_DIM 128
#define H_DIM 512

typedef _Float16 f16x8 __attribute__((ext_vector_type(8)));
typedef _Float16 f16x4 __attribute__((ext_vector_type(4)));
typedef float f32x4 __attribute__((ext_vector_type(4)));

// ---------------------------------------------------------------------------
// prep: dst[j][k] f16 = src[k][j]  (one 512x512 matrix transpose+cast)
// ---------------------------------------------------------------------------
__global__ void prepT(_Float16* __restrict__ dst, const float* __restrict__ src) {
  int idx = blockIdx.x * blockDim.x + threadIdx.x;
  if (idx < 262144) {
    int j = idx >> 9, k = idx & 511;
    dst[idx] = (_Float16)src[k * 512 + j];
  }
}

// ---------------------------------------------------------------------------
// prep: wcat[l][n=512][kc=640]: l0: [wi0|ws0] (256 wide); l1: ws1; l2: ws2 (128)
// ---------------------------------------------------------------------------
__global__ void prep_wcat2(_Float16* __restrict__ dst, const float* __restrict__ wi0,
                           const float* __restrict__ ws0, const float* __restrict__ ws1,
                           const float* __restrict__ ws2) {
  const long total = 3L * 512 * 640;
  for (long idx = (long)blockIdx.x * blockDim.x + threadIdx.x; idx < total;
       idx += (long)gridDim.x * blockDim.x) {
    int l = (int)(idx / 327680);
    int rem = (int)(idx % 327680);
    int n = rem / 640, kc = rem % 640;
    float v = 0.f;
    if (l == 0) {
      if (kc < 128) v = wi0[kc * 512 + n];
      else if (kc < 256) v = ws0[(kc - 128) * 512 + n];
    } else {
      const float* ws = (l == 1) ? ws1 : ws2;
      if (kc < 128) v = ws[kc * 512 + n];
    }
    dst[idx] = (_Float16)v;
  }
}

// ---------------------------------------------------------------------------
// build A' panel f16 (verified; inK=0 -> sxs-only panel of width 128)
// ---------------------------------------------------------------------------
__global__ void build_A(_Float16* __restrict__ Abuf, const float* __restrict__ xin,
                        const float* __restrict__ prev, int n, int inK, int scale,
                        int layer) {
  const int Kcat = inK + 128;
  const long total = (long)n * 64 * Kcat;
  for (long idx = (long)blockIdx.x * blockDim.x + threadIdx.x; idx < total;
       idx += (long)gridDim.x * blockDim.x) {
    int k = (int)(idx % Kcat);
    long r = idx / Kcat;
    int b = (int)(r & 63);
    int t = (int)(r >> 6);
    float v;
    if (k < inK) {
      if (layer == 0) v = xin[((long)b * T_DIM + t) * F_DIM + k];
      else v = prev[((long)(t + scale - 1) * B_DIM + b) * H_DIM + k];
    } else {
      int kk = k - inK;
      int t0 = t + scale - 1;
      float s = 0.f;
      for (int w = 0; w < scale; ++w) s += xin[((long)b * T_DIM + t0 + w) * F_DIM + kk];
      v = s * (1.f / scale);
    }
    Abuf[idx] = (_Float16)v;
  }
}

// ---------------------------------------------------------------------------
// f16 MFMA GEMM (unchanged, verified; B stride fixed 640)
// ---------------------------------------------------------------------------
__global__ __launch_bounds__(256) void gemm_f16(const _Float16* __restrict__ A,
                                                const _Float16* __restrict__ Bt,
                                                float* __restrict__ C, int Mrows,
                                                int Kcat) {
  __shared__ _Float16 As[128][72];
  __shared__ _Float16 Bs[128][72];
  const int tid = threadIdx.x;
  const int tn = blockIdx.x, tm = blockIdx.y;
  const int lane = tid & 63, wid = tid >> 6;
  const int wm = wid >> 1, wn = wid & 1;
  f32x4 acc[4][4] = {};
  const int nK = Kcat >> 6;
  const int lrow = tid >> 3, lkc = (tid & 7) * 8;

  for (int kt = 0; kt < nK; ++kt) {
    for (int r = 0; r < 4; ++r) {
      int row = r * 32 + lrow;
      int grow = tm * 128 + row;
      uint4 va = make_uint4(0u, 0u, 0u, 0u);
      if (grow < Mrows) va = *(const uint4*)&A[(size_t)grow * Kcat + kt * 64 + lkc];
      *(uint4*)&As[row][lkc] = va;
      uint4 vb = *(const uint4*)&Bt[(size_t)(tn * 128 + row) * 640 + kt * 64 + lkc];
      *(uint4*)&Bs[row][lkc] = vb;
    }
    __syncthreads();
#pragma unroll
    for (int kk = 0; kk < 64; kk += 32) {
      f16x8 af[4], bf[4];
#pragma unroll
      for (int mt = 0; mt < 4; ++mt)
        af[mt] = *(const f16x8*)&As[wm * 64 + mt * 16 + (lane & 15)][kk + (lane >> 4) * 8];
#pragma unroll
      for (int nt = 0; nt < 4; ++nt)
        bf[nt] = *(const f16x8*)&Bs[wn * 64 + nt * 16 + (lane & 15)][kk + (lane >> 4) * 8];
#pragma unroll
      for (int mt = 0; mt < 4; ++mt)
#pragma unroll
        for (int nt = 0; nt < 4; ++nt)
          acc[mt][nt] = __builtin_amdgcn_mfma_f32_16x16x32_f16(af[mt], bf[nt], acc[mt][nt], 0, 0, 0);
    }
    __syncthreads();
  }

  const int crow0 = tm * 128 + wm * 64 + (lane >> 4) * 4;
  const int ccol0 = tn * 128 + wn * 64 + (lane & 15);
#pragma unroll
  for (int mt = 0; mt < 4; ++mt)
#pragma unroll
    for (int q = 0; q < 4; ++q) {
      int grow = crow0 + mt * 16 + q;
      if (grow < Mrows) {
#pragma unroll
        for (int nt = 0; nt < 4; ++nt)
          C[(size_t)grow * 512 + ccol0 + nt * 16] = acc[mt][nt][q];
      }
    }
}

// ---------------------------------------------------------------------------
__global__ void zero_cnt(int* __restrict__ c, int ntot) {
  int i = blockIdx.x * blockDim.x + threadIdx.x;
  if (i < ntot) c[i] = 0;
}

// ---------------------------------------------------------------------------
// pipeline: 28 WGs = 7 stages x 4 batch-groups.
// stages: 0 rec0 | 1 proj1a | 2 proj1b | 3 rec1 | 4 proj2a | 5 proj2b | 6 rec2
// rec  : R8-verified body (wh: 10 kb regs + 4 kb LDS + 2 kb L2-streamed),
//        polls proj-b pre availability (l>0), publishes h progress (l<2).
// proj : K-split half (8 kb, wi fully register-resident bfr[4][8]); reads
//        x = producer h (f32, global), stages frag-order LDS, MFMA, RMW-adds
//        into out slice (preS already there). b-half chains after a-half.
// Sync: per-(stage,g) progress counters, publish every 8 steps with
//        vmcnt-drain + agent fence + release store; consumers acquire+fence.
// ---------------------------------------------------------------------------
__global__ __launch_bounds__(512, 2) void pipeline(
    float* __restrict__ out, const _Float16* __restrict__ whT16,
    const _Float16* __restrict__ wiT16, int* __restrict__ prog) {
  __shared__ _Float16 stageBuf[2][16 * 512];   // 32 KB (rec: h dbuf; proj: x dbuf)
  __shared__ _Float16 Blds[4 * 32 * 64 * 8];   // 128 KB (rec only)

  const int wg = blockIdx.x;
  const int s = wg >> 2, g = wg & 2 ? (wg & 3) : (wg & 3);  // g = wg & 3
  const int gg = wg & 3;
  (void)s; (void)g;
  const int stage = wg >> 2;
  const int tid = threadIdx.x;
  const int lane = tid & 63, wid = tid >> 6;
  const int colbase = wid * 64;
  const int bq = lane & 15;
  const int u = lane >> 4;
  const int gnb = wid * 4;

  const int nL[3] = {511, 509, 505};
  const size_t offL[3] = {0, 511ul * 32768, (511ul + 509ul) * 32768};

  if ((stage == 0) || (stage == 3) || (stage == 6)) {
    // ------------------------------ REC l ------------------------------
    const int l = stage / 3;
    const int n = nL[l];
    float* po = out + offL[l];
    const _Float16* whT = whT16 + (size_t)l * 262144;
    int* pub = (l < 2) ? prog + stage * 4 + gg : nullptr;
    const int* src = (l > 0) ? prog + (stage - 1) * 4 + gg : nullptr;
    const int b0g = gg * 16;

    // Blds fill (kb 10..13, frag order)
    {
      uint4* B4 = (uint4*)Blds;
      for (int p = 0; p < 16; ++p) {
        int flat = p * 512 + tid;
        int ll = flat & 63;
        int gn = (flat >> 6) & 31;
        int kbl = flat >> 11;
        B4[flat] = *(const uint4*)&whT[(size_t)(gn * 16 + (ll & 15)) * 512 +
                                       (kbl + 10) * 32 + (ll >> 4) * 8];
      }
    }
    // bfr kb 0..9, residency forced
    f16x8 bfr[4][10];
    {
#pragma unroll
      for (int nt = 0; nt < 4; ++nt) {
        const int j = colbase + nt * 16 + bq;
#pragma unroll
        for (int kb = 0; kb < 10; ++kb)
          bfr[nt][kb] = *(const f16x8*)&whT[(size_t)j * 512 + kb * 32 + u * 8];
      }
#pragma unroll
      for (int nt = 0; nt < 4; ++nt)
#pragma unroll
        for (int kb = 0; kb < 10; ++kb) asm volatile("" : "+v"(bfr[nt][kb]));
    }
    __syncthreads();

    const size_t base = (size_t)(b0g + bq) * 512 + colbase + u * 4;

#define AFRD(kb) (*(const f16x8*)&hs[((kb)*64 + u * 16 + (bq ^ (u & 1))) * 8])
#define BLRD(kb, nt) \
  (*(const f16x8*)&Blds[((((kb)-10) * 32 + gnb + (nt)) * 64 + lane) * 8])
#define GLOAD(kb, nt) \
  (*(const f16x8*)&whT[(size_t)(colbase + (nt)*16 + bq) * 512 + (kb)*32 + u * 8])

    for (int t = 0; t < n; ++t) {
      if (src && (t & 7) == 0) {
        if (tid == 0) {
          int target = t + 8 < n ? t + 8 : n;
          long it = 0;
          while (__hip_atomic_load(src, __ATOMIC_ACQUIRE, __HIP_MEMORY_SCOPE_AGENT) < target)
            if (++it > 100000000L) break;
        }
        __syncthreads();
        __threadfence();
      }

      const float* pc = po + (size_t)t * 32768 + base;
      f32x4 pre[4];
#pragma unroll
      for (int nt = 0; nt < 4; ++nt) pre[nt] = *(const f32x4*)&pc[nt * 16];

      f32x4 acc[4] = {};
      if (t > 0) {
        const _Float16* hs = stageBuf[(t - 1) & 1];
        constexpr int seq[16] = {10, 0, 1, 2, 3, 11, 4, 5, 14, 12, 6, 7, 13, 8, 9, 15};
        constexpr int lnx[16] = {11, -1, -1, -1, -1, 12, -1, -1, -1, 13, -1, -1, -1, -1, -1, -1};
        f16x8 afr[4];
#pragma unroll
        for (int i = 0; i < 4; ++i) afr[i] = AFRD(seq[i]);
        f16x8 blr[4];
#pragma unroll
        for (int nt = 0; nt < 4; ++nt) blr[nt] = BLRD(10, nt);
        f16x8 gfr[4];
#pragma unroll
        for (int nt = 0; nt < 4; ++nt) gfr[nt] = GLOAD(14, nt);

#pragma unroll
        for (int i = 0; i < 16; ++i) {
          const int kb = seq[i];
          f16x8 a = afr[i & 3];
          if (i + 4 < 16) afr[i & 3] = AFRD(seq[i + 4]);
          if (kb < 10) {
#pragma unroll
            for (int nt = 0; nt < 4; ++nt)
              acc[nt] = __builtin_amdgcn_mfma_f32_16x16x32_f16(bfr[nt][kb], a, acc[nt], 0, 0, 0);
          } else if (kb < 14) {
            f16x8 w[4];
#pragma unroll
            for (int nt = 0; nt < 4; ++nt) w[nt] = blr[nt];
            if (lnx[i] >= 0) {
#pragma unroll
              for (int nt = 0; nt < 4; ++nt) blr[nt] = BLRD(lnx[i], nt);
            }
#pragma unroll
            for (int nt = 0; nt < 4; ++nt)
              acc[nt] = __builtin_amdgcn_mfma_f32_16x16x32_f16(w[nt], a, acc[nt], 0, 0, 0);
          } else if (kb == 14) {
            f16x8 w[4];
#pragma unroll
            for (int nt = 0; nt < 4; ++nt) w[nt] = gfr[nt];
#pragma unroll
            for (int nt = 0; nt < 4; ++nt) gfr[nt] = GLOAD(15, nt);
#pragma unroll
            for (int nt = 0; nt < 4; ++nt)
              acc[nt] = __builtin_amdgcn_mfma_f32_16x16x32_f16(w[nt], a, acc[nt], 0, 0, 0);
          } else {
#pragma unroll
            for (int nt = 0; nt < 4; ++nt)
              acc[nt] = __builtin_amdgcn_mfma_f32_16x16x32_f16(gfr[nt], a, acc[nt], 0, 0, 0);
          }
        }
      }

      _Float16* hw = stageBuf[t & 1];
      float* pw = po + (size_t)t * 32768 + base;
#pragma unroll
      for (int nt = 0; nt < 4; ++nt) {
        const int J = colbase + nt * 16 + u * 4;
        const int slot = (J >> 5) * 64 + ((J >> 3) & 3) * 16 + (bq ^ ((J >> 3) & 1));
        f16x4 h4;
#pragma unroll
        for (int q = 0; q < 4; ++q) {
          float a = acc[nt][q] + pre[nt][q];
          float e = __builtin_amdgcn_exp2f(a * 2.8853900817779268f);
          float h = 1.f - 2.f * __builtin_amdgcn_rcpf(e + 1.f);
          acc[nt][q] = h;
          h4[q] = (_Float16)h;
        }
        *(f16x4*)&hw[slot * 8 + (J & 7)] = h4;
        *(f32x4*)&pw[nt * 16] = acc[nt];
      }

      if (pub && (((t & 7) == 7) || (t == n - 1))) {
        asm volatile("s_waitcnt vmcnt(0) lgkmcnt(0)\n\ts_barrier" ::: "memory");
        __threadfence();
        if (tid == 0)
          __hip_atomic_store(pub, t + 1, __ATOMIC_RELEASE, __HIP_MEMORY_SCOPE_AGENT);
      } else {
        asm volatile("s_waitcnt lgkmcnt(0)\n\ts_barrier" ::: "memory");
      }
    }
#undef AFRD
#undef BLRD
#undef GLOAD
  } else {
    // ------------------------------ PROJ l, half ha ------------------------------
    const int l = (stage <= 2) ? 1 : 2;
    const int ha = (stage == 2 || stage == 5) ? 1 : 0;
    const int n = nL[l], nprev = nL[l - 1];
    const int off = (l == 1) ? 1 : 3;
    const float* xsrc = out + offL[l - 1];
    float* pdst = out + offL[l];
    const _Float16* wiT = wiT16 + (size_t)(l - 1) * 262144;
    int* pub = prog + stage * 4 + gg;
    const int* srcX = prog + ((l == 1) ? 0 : 3) * 4 + gg;        // rec l-1
    const int* srcA = ha ? (prog + (stage - 1) * 4 + gg) : nullptr;  // a-half

    // wi frags for this K-half: fully register-resident
    f16x8 bfr8[4][8];
    {
#pragma unroll
      for (int nt = 0; nt < 4; ++nt) {
        const int j = colbase + nt * 16 + bq;
#pragma unroll
        for (int kb = 0; kb < 8; ++kb)
          bfr8[nt][kb] = *(const f16x8*)&wiT[(size_t)j * 512 + (ha * 8 + kb) * 32 + u * 8];
      }
#pragma unroll
      for (int nt = 0; nt < 4; ++nt)
#pragma unroll
        for (int kb = 0; kb < 8; ++kb) asm volatile("" : "+v"(bfr8[nt][kb]));
    }

    // x staging coords: thread covers (bx, k_local = jbi*8 .. +8)
    const int bx = tid & 15;
    const int jbi = tid >> 4;  // 0..31
    const int slotW = (jbi >> 2) * 64 + (jbi & 3) * 16 + (bx ^ (jbi & 1));
    const size_t xrowbase = (size_t)(gg * 16 + bx) * 512 + ha * 256 + jbi * 8;
    const size_t base = (size_t)(gg * 16 + bq) * 512 + colbase + u * 4;

    // prologue: poll + stage x(0)
    if (tid == 0) {
      int target = 9 + off < nprev ? 9 + off : nprev;
      long it = 0;
      while (__hip_atomic_load(srcX, __ATOMIC_ACQUIRE, __HIP_MEMORY_SCOPE_AGENT) < target)
        if (++it > 100000000L) break;
      if (srcA) {
        int ta = 8 < n ? 8 : n;
        it = 0;
        while (__hip_atomic_load(srcA, __ATOMIC_ACQUIRE, __HIP_MEMORY_SCOPE_AGENT) < ta)
          if (++it > 100000000L) break;
      }
    }
    __syncthreads();
    __threadfence();
    {
      const float* xr = xsrc + (size_t)off * 32768 + xrowbase;
      float4 xa = *(const float4*)&xr[0];
      float4 xb = *(const float4*)&xr[4];
      f16x8 xh;
      xh[0] = (_Float16)xa.x; xh[1] = (_Float16)xa.y;
      xh[2] = (_Float16)xa.z; xh[3] = (_Float16)xa.w;
      xh[4] = (_Float16)xb.x; xh[5] = (_Float16)xb.y;
      xh[6] = (_Float16)xb.z; xh[7] = (_Float16)xb.w;
      *(f16x8*)&stageBuf[0][slotW * 8] = xh;
    }
    asm volatile("s_waitcnt lgkmcnt(0)\n\ts_barrier" ::: "memory");

#define AFP(kb) \
  (*(const f16x8*)&hs[((kb)*64 + u * 16 + (bq ^ (u & 1))) * 8])

    for (int t = 0; t < n; ++t) {
      if ((t & 7) == 0 && t) {
        if (tid == 0) {
          int target = t + 9 + off < nprev ? t + 9 + off : nprev;
          long it = 0;
          while (__hip_atomic_load(srcX, __ATOMIC_ACQUIRE, __HIP_MEMORY_SCOPE_AGENT) < target)
            if (++it > 100000000L) break;
          if (srcA) {
            int ta = t + 8 < n ? t + 8 : n;
            it = 0;
            while (__hip_atomic_load(srcA, __ATOMIC_ACQUIRE, __HIP_MEMORY_SCOPE_AGENT) < ta)
              if (++it > 100000000L) break;
          }
        }
        __syncthreads();
        __threadfence();
      }

      // issue x(t+1) loads
      const bool havN = (t + 1 < n);
      float4 xa, xb;
      if (havN) {
        const float* xr = xsrc + (size_t)(t + 1 + off) * 32768 + xrowbase;
        xa = *(const float4*)&xr[0];
        xb = *(const float4*)&xr[4];
      }

      // MFMA over this K-half
      f32x4 acc[4] = {};
      {
        const _Float16* hs = stageBuf[t & 1];
        f16x8 afr[4];
#pragma unroll
        for (int i = 0; i < 4; ++i) afr[i] = AFP(i);
#pragma unroll
        for (int kb = 0; kb < 8; ++kb) {
          f16x8 a = afr[kb & 3];
          if (kb < 4) afr[kb & 3] = AFP(kb + 4);
#pragma unroll
          for (int nt = 0; nt < 4; ++nt)
            acc[nt] = __builtin_amdgcn_mfma_f32_16x16x32_f16(bfr8[nt][kb], a, acc[nt], 0, 0, 0);
        }
      }

      // RMW into out slice (preS or preS+partial_a already there)
      float* pw = pdst + (size_t)t * 32768 + base;
#pragma unroll
      for (int nt = 0; nt < 4; ++nt) {
        f32x4 v = *(const f32x4*)&pw[nt * 16];
        v += acc[nt];
        *(f32x4*)&pw[nt * 16] = v;
      }

      // stage x(t+1)
      if (havN) {
        f16x8 xh;
        xh[0] = (_Float16)xa.x; xh[1] = (_Float16)xa.y;
        xh[2] = (_Float16)xa.z; xh[3] = (_Float16)xa.w;
        xh[4] = (_Float16)xb.x; xh[5] = (_Float16)xb.y;
        xh[6] = (_Float16)xb.z; xh[7] = (_Float16)xb.w;
        *(f16x8*)&stageBuf[(t + 1) & 1][slotW * 8] = xh;
      }

      if (((t & 7) == 7) || (t == n - 1)) {
        asm volatile("s_waitcnt vmcnt(0) lgkmcnt(0)\n\ts_barrier" ::: "memory");
        __threadfence();
        if (tid == 0)
          __hip_atomic_store(pub, t + 1, __ATOMIC_RELEASE, __HIP_MEMORY_SCOPE_AGENT);
      } else {
        asm volatile("s_waitcnt lgkmcnt(0)\n\ts_barrier" ::: "memory");
      }
    }
#undef AFP
  }
}

// ---------------------------------------------------------------------------
extern "C" void kernel_launch(void* const* d_in, const int* in_sizes, int n_in,
                              void* d_out, int out_size, void* d_ws, size_t ws_size,
                              hipStream_t stream) {
  const float* inputs = (const float*)d_in[0];
  const float* wi[3] = {(const float*)d_in[1], (const float*)d_in[4], (const float*)d_in[7]};
  const float* wsm[3] = {(const float*)d_in[2], (const float*)d_in[5], (const float*)d_in[8]};
  const float* wh[3] = {(const float*)d_in[3], (const float*)d_in[6], (const float*)d_in[9]};
  float* out = (float*)d_out;

  char* wsp = (char*)d_ws;
  _Float16* whT16 = (_Float16*)wsp;                   // 3*512*512*2 = 1,572,864
  _Float16* wiT16 = (_Float16*)(wsp + 1572864);       // 2*512*512*2 = 1,048,576
  _Float16* wcat = (_Float16*)(wsp + 2621440);        // 3*512*640*2 = 1,966,080
  int* prog = (int*)(wsp + 4587520);                  // 24 ints
  _Float16* Abuf = (_Float16*)(wsp + 4587776);        // 32704*640*2 max

  zero_cnt<<<1, 64, 0, stream>>>(prog, 24);
  for (int l = 0; l < 3; ++l)
    prepT<<<1024, 256, 0, stream>>>(whT16 + (size_t)l * 262144, wh[l]);
  prepT<<<1024, 256, 0, stream>>>(wiT16, wi[1]);
  prepT<<<1024, 256, 0, stream>>>(wiT16 + 262144, wi[2]);
  prep_wcat2<<<1024, 256, 0, stream>>>(wcat, wi[0], wsm[0], wsm[1], wsm[2]);

  const int nL[3] = {511, 509, 505};
  const long offL[3] = {0L, 511L * 32768, (511L + 509L) * 32768};

  // layer0 full pre = [x|sx1] @ [wi0|ws0]
  build_A<<<4096, 256, 0, stream>>>(Abuf, inputs, nullptr, nL[0], 128, 1, 0);
  gemm_f16<<<dim3(4, (nL[0] * 64 + 127) / 128), 256, 0, stream>>>(
      Abuf, wcat, out, nL[0] * 64, 256);
  // layer1 preS = sx2 @ ws1
  build_A<<<2048, 256, 0, stream>>>(Abuf, inputs, nullptr, nL[1], 0, 2, 1);
  gemm_f16<<<dim3(4, (nL[1] * 64 + 127) / 128), 256, 0, stream>>>(
      Abuf, wcat + 512 * 640, out + offL[1], nL[1] * 64, 128);
  // layer2 preS = sx4 @ ws2
  build_A<<<2048, 256, 0, stream>>>(Abuf, inputs, nullptr, nL[2], 0, 4, 1);
  gemm_f16<<<dim3(4, (nL[2] * 64 + 127) / 128), 256, 0, stream>>>(
      Abuf, wcat + 2 * 512 * 640, out + offL[2], nL[2] * 64, 128);

  // fused 7-stage pipeline: rec0|proj1a|proj1b|rec1|proj2a|proj2b|rec2 x 4 groups
  pipeline<<<28, 512, 0, stream>>>(out, whT16, wiT16, prog);
}